// Round 8
// baseline (165.376 us; speedup 1.0000x reference)
//
#include <hip/hip_runtime.h>
#include <math.h>

// Problem constants
// DIM=256, QK=256, HEADS=8, NWIN=7, TOPK=4, H=W=112, hw=ww=16, p2=49, w2=256, hd=32
//
// Data flow (all MFMA operands packed bf16, K-contiguous):
//   pack1:    w_qkv -> wtq (T bf16), w_o -> wto, zero q_win/k_win
//   gemm<1>:  x (fp32) staged to LDS as bf16 tile; ALL Wt frags hoisted to
//             regs in the prologue (latency hidden under staging+barrier);
//             K-loop = ds_read + MFMA only. -> Qp (log2e/16 baked), Kp, vbf;
//             V-blocks LDS-transpose to Vt; Q/K blocks window channel sums
//             via shfl + atomicAdd.
//   routing_topk: window routing indices
//   attn:     flash attention v14 (= v13 pipeline + deferred quad-reduce):
//             16-stage QKSM(u+1)/PV(u) pipeline, per-nt P ping-pong; row-sum
//             kept as per-lane partials in-loop, single quad-reduce (8 shfl)
//             after the K-loop. LDS 36864 B.
//   gemm<0>:  prebf @ wto -> out fp32 (same hoisted-Wt structure)

typedef __bf16 bf16x8 __attribute__((ext_vector_type(8)));
typedef __bf16 bf16x4 __attribute__((ext_vector_type(4)));
typedef float f32x4 __attribute__((ext_vector_type(4)));

// ---------------------------------------------------------------------------
// pack1: grid 768+256+98 blocks x 64 threads
// ---------------------------------------------------------------------------
__global__ __launch_bounds__(64)
void pack1(const float* __restrict__ w_qkv, const float* __restrict__ w_o,
           __bf16* __restrict__ wtq, __bf16* __restrict__ wto,
           float* __restrict__ qkwin) {
    const int b = blockIdx.x;
    const int t = threadIdx.x;
    if (b < 768) {
        int n = b;
        int k = t * 4;
        bf16x4 o;
        o[0] = (__bf16)w_qkv[(k + 0) * 768 + n];
        o[1] = (__bf16)w_qkv[(k + 1) * 768 + n];
        o[2] = (__bf16)w_qkv[(k + 2) * 768 + n];
        o[3] = (__bf16)w_qkv[(k + 3) * 768 + n];
        *(bf16x4*)(wtq + (size_t)n * 256 + k) = o;
    } else if (b < 1024) {
        int n = b - 768;
        int k = t * 4;
        bf16x4 o;
        o[0] = (__bf16)w_o[(k + 0) * 256 + n];
        o[1] = (__bf16)w_o[(k + 1) * 256 + n];
        o[2] = (__bf16)w_o[(k + 2) * 256 + n];
        o[3] = (__bf16)w_o[(k + 3) * 256 + n];
        *(bf16x4*)(wto + (size_t)n * 256 + k) = o;
    } else {
        int idx = (b - 1024) * 64 + t;
        *(float4*)(qkwin + (size_t)idx * 4) = (float4){0.f, 0.f, 0.f, 0.f};
    }
}

// ---------------------------------------------------------------------------
// bf16 MFMA GEMM: D[n][m] = Wt[n][k] . A[m][k]  (K=256), +bias.
// Block 256 thr = 4 waves. Wave: 32 n (2 frags) x 64 m (4 frags), 8 K-steps.
// A-tile (64 x 256) staged once into LDS (bf16); ALL 16 Wt frags loaded to
// registers BEFORE the barrier (their ~200-300cy L2 latency hides under the
// staging + sync), so the K-loop is pure ds_read_b128 + MFMA.
// LDS: As[64][264] (33792 B) unioned with Vs[128][72] (As dead after K-loop;
// barrier before Vs writes).
// ---------------------------------------------------------------------------
template<int QKV>
__global__ __launch_bounds__(256)
void gemm_bf16(const __bf16* __restrict__ A,
               const float* __restrict__ Ax,
               const __bf16* __restrict__ Wt,
               const float* __restrict__ bias,
               float* __restrict__ C, int N,
               __bf16* __restrict__ Qp,
               __bf16* __restrict__ Kp,
               __bf16* __restrict__ vbf,
               __bf16* __restrict__ Vt,
               float* __restrict__ q_win,
               float* __restrict__ k_win) {
    const int t = threadIdx.x & 63;
    const int wv = threadIdx.x >> 6;
    const int l16 = t & 15, quad = t >> 4;
    const int m0 = blockIdx.x * 64;
    const int n0 = blockIdx.y * 128 + wv * 32;

    __shared__ __align__(16) char smem[33792];            // As (33792) | Vs (18432)
    __bf16 (*const As)[264] = (__bf16(*)[264])smem;       // staged A-tile, padded
    __bf16 (*const Vs)[72]  = (__bf16(*)[72])smem;        // V-transpose staging

    // ---- stage A-tile (64 rows x 256) into LDS ----
    if (QKV == 1) {
        // fp32 x (image layout) -> bf16 LDS; block spans one window p
        const int p = m0 >> 8, pixbase = m0 & 255;
        const int rowbase0 = (p / 7) * 16 * 112 + (p % 7) * 16;
#pragma unroll
        for (int it = 0; it < 16; it++) {
            const int j = it * 1024 + threadIdx.x * 4;    // flat float idx
            const int r = j >> 8, col = j & 255;
            const int pix = pixbase + r;
            const int ir = rowbase0 + (pix >> 4) * 112 + (pix & 15);
            const float4 f = *(const float4*)(Ax + (size_t)ir * 256 + col);
            bf16x4 o;
            o[0] = (__bf16)f.x; o[1] = (__bf16)f.y;
            o[2] = (__bf16)f.z; o[3] = (__bf16)f.w;
            *(bf16x4*)&As[r][col] = o;
        }
    } else {
#pragma unroll
        for (int it = 0; it < 8; it++) {
            const int j = it * 2048 + threadIdx.x * 8;    // flat bf16 idx
            const int r = j >> 8, col = j & 255;
            *(bf16x8*)&As[r][col] = *(const bf16x8*)(A + (size_t)(m0 + r) * 256 + col);
        }
    }

    // ---- hoist ALL Wt frags (16 x bf16x8 = 64 VGPR) before the barrier ----
    bf16x8 Af[8][2];
#pragma unroll
    for (int ks = 0; ks < 8; ks++)
#pragma unroll
        for (int km = 0; km < 2; km++)
            Af[ks][km] = *(const bf16x8*)(Wt + (size_t)(n0 + km * 16 + l16) * 256 + ks * 32 + quad * 8);

    __syncthreads();

    f32x4 acc[2][4];
#pragma unroll
    for (int km = 0; km < 2; km++)
#pragma unroll
        for (int nt = 0; nt < 4; nt++) acc[km][nt] = (f32x4){0.f, 0.f, 0.f, 0.f};

    // ---- K-loop: pure LDS reads + MFMA (Wt already in regs) ----
#pragma unroll
    for (int ks = 0; ks < 8; ks++) {
        bf16x8 Bf[4];
#pragma unroll
        for (int nt = 0; nt < 4; nt++)
            Bf[nt] = *(const bf16x8*)&As[nt * 16 + l16][ks * 32 + quad * 8];

#pragma unroll
        for (int km = 0; km < 2; km++)
#pragma unroll
            for (int nt = 0; nt < 4; nt++)
                acc[km][nt] = __builtin_amdgcn_mfma_f32_16x16x32_bf16(
                    Af[ks][km], Bf[nt], acc[km][nt], 0, 0, 0);
    }

    // As is dead; V-blocks will reuse the LDS as Vs
    if (QKV == 1 && blockIdx.y >= 4) __syncthreads();

    float ws[2][4];   // window channel sums (QKV=1, Q/K blocks)
#pragma unroll
    for (int km = 0; km < 2; km++)
#pragma unroll
        for (int j = 0; j < 4; j++) ws[km][j] = 0.f;

#pragma unroll
    for (int km = 0; km < 2; km++) {
        const int n = n0 + km * 16 + quad * 4;
        float4 b4 = *(const float4*)(bias + n);
#pragma unroll
        for (int nt = 0; nt < 4; nt++) {
            const int m = m0 + nt * 16 + l16;
            float v0 = acc[km][nt][0] + b4.x;
            float v1 = acc[km][nt][1] + b4.y;
            float v2 = acc[km][nt][2] + b4.z;
            float v3 = acc[km][nt][3] + b4.w;
            if (QKV == 0) {
                float4 o = {v0, v1, v2, v3};
                *(float4*)(C + (size_t)m * N + n) = o;
            } else {
                const int p = m >> 8, pix = m & 255;
                if (n0 < 512) {
                    ws[km][0] += v0; ws[km][1] += v1;
                    ws[km][2] += v2; ws[km][3] += v3;
                }
                if (n0 < 256) {            // Q -> Qp, log2e/16 scale baked in
                    const float s = 1.4426950408889634f / 16.0f;
                    int h = n >> 5, cc = n & 31;
                    bf16x4 o;
                    o[0] = (__bf16)(v0 * s); o[1] = (__bf16)(v1 * s);
                    o[2] = (__bf16)(v2 * s); o[3] = (__bf16)(v3 * s);
                    *(bf16x4*)(Qp + ((size_t)((p * 8 + h) * 256 + pix)) * 32 + cc) = o;
                } else if (n0 < 512) {     // K -> Kp
                    int n2 = n - 256;
                    int h = n2 >> 5, cc = n2 & 31;
                    bf16x4 o;
                    o[0] = (__bf16)v0; o[1] = (__bf16)v1;
                    o[2] = (__bf16)v2; o[3] = (__bf16)v3;
                    *(bf16x4*)(Kp + ((size_t)((p * 8 + h) * 256 + pix)) * 32 + cc) = o;
                } else {                   // V -> vbf bf16 image + LDS stash
                    int n2 = n - 512;
                    int imgrow = ((p / 7) * 16 + (pix >> 4)) * 112 + (p % 7) * 16 + (pix & 15);
                    bf16x4 o;
                    o[0] = (__bf16)v0; o[1] = (__bf16)v1;
                    o[2] = (__bf16)v2; o[3] = (__bf16)v3;
                    *(bf16x4*)(vbf + (size_t)imgrow * 256 + n2) = o;
                    const int cbase = wv * 32 + km * 16 + quad * 4;   // 0..127
                    const int pb = nt * 16 + l16;                      // 0..63
                    Vs[cbase + 0][pb] = o[0];
                    Vs[cbase + 1][pb] = o[1];
                    Vs[cbase + 2][pb] = o[2];
                    Vs[cbase + 3][pb] = o[3];
                }
            }
        }
    }

    if (QKV == 1 && n0 < 512) {
        const int pblk = m0 >> 8;
#pragma unroll
        for (int km = 0; km < 2; km++) {
#pragma unroll
            for (int j = 0; j < 4; j++) {
                float s = ws[km][j];
                s += __shfl_xor(s, 1);
                s += __shfl_xor(s, 2);
                s += __shfl_xor(s, 4);
                s += __shfl_xor(s, 8);
                ws[km][j] = s;
            }
            if (l16 == 0) {
                const int n = n0 + km * 16 + quad * 4;
                float* dst = (n < 256) ? (q_win + pblk * 256 + n)
                                       : (k_win + pblk * 256 + (n - 256));
                atomicAdd(dst + 0, ws[km][0]);
                atomicAdd(dst + 1, ws[km][1]);
                atomicAdd(dst + 2, ws[km][2]);
                atomicAdd(dst + 3, ws[km][3]);
            }
        }
    }

    if (QKV == 1 && blockIdx.y >= 4) {
        __syncthreads();
        const int p_ = m0 >> 8, qt_ = (m0 >> 6) & 3;
        const int vb = blockIdx.y * 128 - 512;   // 0 or 128
#pragma unroll
        for (int rep = 0; rep < 4; rep++) {
            int id = rep * 256 + threadIdx.x;
            int row = id >> 3, c8 = (id & 7) * 8;
            int hh = (vb + row) >> 5, c32 = (vb + row) & 31;
            bf16x8 val = *(const bf16x8*)&Vs[row][c8];
            *(bf16x8*)(Vt + ((size_t)((p_ * 8 + hh) * 32 + c32)) * 256 + qt_ * 64 + c8) = val;
        }
    }
}

// ---------------------------------------------------------------------------
// Routing: grid 49, 64 threads; lane j = dot(q_win[r], k_win[j]); lane 0 top-4.
// (q_win/k_win are unscaled channel SUMS; dropped factors are positive
//  monotone -> same top-4 set, which is all attn uses.)
// ---------------------------------------------------------------------------
__global__ __launch_bounds__(64)
void routing_topk(const float* __restrict__ q_win,
                  const float* __restrict__ k_win,
                  int* __restrict__ top_idx) {
    const int r = blockIdx.x;
    const int j = threadIdx.x;
    __shared__ float vals[64];

    float d = -1e30f;
    if (j < 49) {
        const float4* qp = (const float4*)(q_win + r * 256);
        const float4* kp = (const float4*)(k_win + j * 256);
        float s = 0.f;
#pragma unroll
        for (int c = 0; c < 64; c++) {
            float4 a = qp[c], b = kp[c];
            s += a.x * b.x + a.y * b.y + a.z * b.z + a.w * b.w;
        }
        d = s;
    }
    vals[j] = d;
    __syncthreads();
    if (j == 0) {
        float bv0 = -1e30f, bv1 = -1e30f, bv2 = -1e30f, bv3 = -1e30f;
        int bi0 = 0, bi1 = 0, bi2 = 0, bi3 = 0;
        for (int q = 0; q < 49; q++) {
            float v = vals[q];
            if (v > bv0) {
                bv3 = bv2; bi3 = bi2; bv2 = bv1; bi2 = bi1; bv1 = bv0; bi1 = bi0;
                bv0 = v; bi0 = q;
            } else if (v > bv1) {
                bv3 = bv2; bi3 = bi2; bv2 = bv1; bi2 = bi1; bv1 = v; bi1 = q;
            } else if (v > bv2) {
                bv3 = bv2; bi3 = bi2; bv2 = v; bi2 = q;
            } else if (v > bv3) {
                bv3 = v; bi3 = q;
            }
        }
        top_idx[r * 4 + 0] = bi0;
        top_idx[r * 4 + 1] = bi1;
        top_idx[r * 4 + 2] = bi2;
        top_idx[r * 4 + 3] = bi3;
    }
}

// ---------------------------------------------------------------------------
// MFMA flash attention v14: v13's 16-stage QKSM/PV pipeline + deferred
// quad-reduce. 4 waves/block (256 thr), grid 1568 XCD-swizzled. Wave wv owns
// routed window sels[wv]. Per-nt P ping-pong; loop body QKSM(u+1) -> PV(u).
// Row-sum: per-lane partials accumulated in lstate[] (NO in-loop shfl);
// one 8-shfl quad-reduce after the K-loop (red.l stays quad-uniform).
// K prefetched 1 chunk ahead; V loaded after its last use. Fixed-base
// softmax p=exp2(S). LDS 36864 B; no launch_bounds cap (round-5 lesson).
// ---------------------------------------------------------------------------
#define PLDS_PITCH 68
#define HALO_PITCH 36   // shorts per halo pixel (32 ch + 4 pad; 72 B)

__global__ __launch_bounds__(256)
void attn_mfma(const __bf16* __restrict__ Qp,
               const __bf16* __restrict__ Kp,
               const __bf16* __restrict__ Vt,
               const int* __restrict__ top_idx,
               const __bf16* __restrict__ vbf,
               const float* __restrict__ lw,
               const float* __restrict__ lb,
               __bf16* __restrict__ prebf) {
    const int bb = blockIdx.x;
    const int qt = bb / 392;
    const int ph = bb - qt * 392;
    const int p = ph >> 3;
    const int h = ph & 7;
    const int t = threadIdx.x & 63;
    const int wv = threadIdx.x >> 6;
    const int l16 = t & 15, quad = t >> 4;

    __shared__ union {
        unsigned short Plds[4][2][16 * PLDS_PITCH];   // 17408 B: per-wave P ping-pong
        struct {
            f32x4 O[4][2][4][64];                     // 32768 B: [wv][mt][nt][t]
            float l[4][4][64];                        //  4096 B: [wv][nt][t]
        } red;                                        // 36864 B
        __bf16 Hs[108 * HALO_PITCH];                  //  7776 B (overlaid later)
    } U;                                              // union size 36864 B

    bf16x8 Qf[4];
#pragma unroll
    for (int nt = 0; nt < 4; nt++)
        Qf[nt] = *(const bf16x8*)(Qp + ((size_t)((p * 8 + h) * 256 + qt * 64 + nt * 16 + l16)) * 32 + quad * 8);

    const int sel = top_idx[p * 4 + wv];
    const __bf16* const Kb = Kp + ((size_t)(sel * 8 + h)) * 8192;
    const __bf16* const Vb = Vt + ((size_t)(sel * 8 + h)) * 8192;

    float lstate[4] = {0.f, 0.f, 0.f, 0.f};
    f32x4 O[2][4];
#pragma unroll
    for (int mt = 0; mt < 2; mt++)
#pragma unroll
        for (int nt = 0; nt < 4; nt++) O[mt][nt] = (f32x4){0.f, 0.f, 0.f, 0.f};

    // preload K chunk 0 and V chunk 0
    bf16x8 Kf[4], Kn[4], Vf[2][2];
#pragma unroll
    for (int km = 0; km < 4; km++)
        Kf[km] = *(const bf16x8*)(Kb + (size_t)(km * 16 + l16) * 32 + quad * 8);
#pragma unroll
    for (int ks = 0; ks < 2; ks++)
#pragma unroll
        for (int mt = 0; mt < 2; mt++)
            Vf[ks][mt] = *(const bf16x8*)(Vb + (size_t)(mt * 16 + l16) * 256 + ks * 32 + quad * 8);

    // stage helpers (inlined; all args compile-time under full unroll)
    auto QKSM = [&](int ntv, int par) {
        f32x4 S[4];
        __builtin_amdgcn_s_setprio(1);
#pragma unroll
        for (int km = 0; km < 4; km++)
            S[km] = __builtin_amdgcn_mfma_f32_16x16x32_bf16(
                Kf[km], Qf[ntv], (f32x4){0.f, 0.f, 0.f, 0.f}, 0, 0, 0);
        __builtin_amdgcn_s_setprio(0);
        unsigned short* const Pp = U.Plds[wv][par];
        float rs = 0.f;
#pragma unroll
        for (int km = 0; km < 4; km++) {
            union { unsigned short u_[4]; ushort4 v; } pk;
#pragma unroll
            for (int r = 0; r < 4; r++) {
                float pv = __builtin_amdgcn_exp2f(S[km][r]);
                rs += pv;
                pk.u_[r] = __builtin_bit_cast(unsigned short, (__bf16)pv);
            }
            *(ushort4*)&Pp[l16 * PLDS_PITCH + km * 16 + quad * 4] = pk.v;
        }
        lstate[ntv] += rs;   // per-lane partial; quad-reduce deferred
    };

    auto PV = [&](int ntv, int par) {
        unsigned short* const Pp = U.Plds[wv][par];
#pragma unroll
        for (int ks = 0; ks < 2; ks++) {
            const int idx = l16 * PLDS_PITCH + ks * 32 + quad * 8;
            union { ushort4 u4[2]; bf16x8 v; } pu;
            pu.u4[0] = *(const ushort4*)&Pp[idx];
            pu.u4[1] = *(const ushort4*)&Pp[idx + 4];
            __builtin_amdgcn_s_setprio(1);
#pragma unroll
            for (int mt = 0; mt < 2; mt++)
                O[mt][ntv] = __builtin_amdgcn_mfma_f32_16x16x32_bf16(
                    Vf[ks][mt], pu.v, O[mt][ntv], 0, 0, 0);
            __builtin_amdgcn_s_setprio(0);
        }
    };

    // prologue: stage 0 -> buf 0
    QKSM(0, 0);

#pragma unroll
    for (int u = 0; u < 16; u++) {
        const int kc = u >> 2, nt = u & 3;
        const int par = u & 1;

        // K prefetch for chunk kc+1 (used 4 stages later)
        if (nt == 0 && kc < 3) {
#pragma unroll
            for (int km = 0; km < 4; km++)
                Kn[km] = *(const bf16x8*)(Kb + (size_t)((kc + 1) * 64 + km * 16 + l16) * 32 + quad * 8);
        }

        if (u < 15) {
            const int ntn = (u + 1) & 3;
            if (ntn == 0) {   // entering next chunk for QK
#pragma unroll
                for (int km = 0; km < 4; km++) Kf[km] = Kn[km];
            }
            QKSM(ntn, par ^ 1);
        }

        PV(nt, par);

        if (nt == 3 && kc < 3) {
            // Vf free after this PV; load next chunk's V
#pragma unroll
            for (int ks = 0; ks < 2; ks++)
#pragma unroll
                for (int mt = 0; mt < 2; mt++)
                    Vf[ks][mt] = *(const bf16x8*)(Vb + (size_t)(mt * 16 + l16) * 256 + (kc + 1) * 64 + ks * 32 + quad * 8);
        }
    }

    // ---- deferred quad-reduce of row sums (8 shfls total) ----
#pragma unroll
    for (int nt2 = 0; nt2 < 4; nt2++) {
        float rs = lstate[nt2];
        rs += __shfl_xor(rs, 16);
        rs += __shfl_xor(rs, 32);
        lstate[nt2] = rs;
    }

    // ---- block-wide combine: partials -> LDS (Plds is dead, reuse) ----
    __syncthreads();
#pragma unroll
    for (int mt = 0; mt < 2; mt++)
#pragma unroll
        for (int nt = 0; nt < 4; nt++)
            U.red.O[wv][mt][nt][t] = O[mt][nt];
#pragma unroll
    for (int nt = 0; nt < 4; nt++)
        U.red.l[wv][nt][t] = lstate[nt];
    __syncthreads();

    // ---- pull combined O,l for this wave's q-row group (nt = wv) to regs ----
    const int nt = wv;
    const float ltot = U.red.l[0][nt][t] + U.red.l[1][nt][t]
                     + U.red.l[2][nt][t] + U.red.l[3][nt][t];
    const float inv = 1.f / ltot;
    f32x4 Osum[2];
#pragma unroll
    for (int mt = 0; mt < 2; mt++) {
        f32x4 o = U.red.O[0][mt][nt][t];
#pragma unroll
        for (int v = 1; v < 4; v++) {
            f32x4 ov = U.red.O[v][mt][nt][t];
            o[0] += ov[0]; o[1] += ov[1]; o[2] += ov[2]; o[3] += ov[3];
        }
        Osum[mt] = o;
    }
    __syncthreads();   // red dead -> Hs may overlay

    // ---- stage 6x18 halo rows into Hs (direct global->LDS) ----
    const int pr = p / 7, pc = p % 7;
    if (threadIdx.x < 108) {
        const int i = threadIdx.x;
        int hy = i / 18, hx = i - hy * 18;
        int gy = pr * 16 + qt * 4 - 1 + hy;
        int gx = pc * 16 - 1 + hx;
        union { bf16x4 v4[8]; bf16x8 v8[4]; uint4 q[4]; } u;
        u.q[0] = (uint4){0u, 0u, 0u, 0u};
        u.q[1] = (uint4){0u, 0u, 0u, 0u};
        u.q[2] = (uint4){0u, 0u, 0u, 0u};
        u.q[3] = (uint4){0u, 0u, 0u, 0u};
        if (gy >= 0 && gy < 112 && gx >= 0 && gx < 112) {
            const __bf16* src = vbf + ((size_t)(gy * 112 + gx)) * 256 + h * 32;
            u.v8[0] = *(const bf16x8*)src;
            u.v8[1] = *(const bf16x8*)(src + 8);
            u.v8[2] = *(const bf16x8*)(src + 16);
            u.v8[3] = *(const bf16x8*)(src + 24);
        }
#pragma unroll
        for (int j = 0; j < 8; j++)
            *(bf16x4*)&U.Hs[i * HALO_PITCH + j * 4] = u.v4[j];
    }
    __syncthreads();

    // ---- epilogue: LePE 3x3 dwconv from Hs + normalize + store ----
    const int himg = pr * 16 + qt * 4 + nt, wimg = pc * 16 + l16;
#pragma unroll
    for (int mt = 0; mt < 2; mt++) {
        const int c = h * 32 + mt * 16 + quad * 4;
        const float4 lbv = *(const float4*)(lb + c);
        float a0 = lbv.x, a1 = lbv.y, a2 = lbv.z, a3 = lbv.w;
#pragma unroll
        for (int dh = 0; dh < 3; dh++)
#pragma unroll
            for (int dw = 0; dw < 3; dw++) {
                const float4 w4 = *(const float4*)(lw + (dh * 3 + dw) * 256 + c);
                const bf16x4 v4 = *(const bf16x4*)&U.Hs[((nt + dh) * 18 + l16 + dw) * HALO_PITCH + mt * 16 + quad * 4];
                a0 += (float)v4[0] * w4.x;
                a1 += (float)v4[1] * w4.y;
                a2 += (float)v4[2] * w4.z;
                a3 += (float)v4[3] * w4.w;
            }
        bf16x4 ob;
        ob[0] = (__bf16)(Osum[mt][0] * inv + a0);
        ob[1] = (__bf16)(Osum[mt][1] * inv + a1);
        ob[2] = (__bf16)(Osum[mt][2] * inv + a2);
        ob[3] = (__bf16)(Osum[mt][3] * inv + a3);
        *(bf16x4*)(prebf + ((size_t)(himg * 112 + wimg)) * 256 + c) = ob;
    }
}

// ---------------------------------------------------------------------------
extern "C" void kernel_launch(void* const* d_in, const int* in_sizes, int n_in,
                              void* d_out, int out_size, void* d_ws, size_t ws_size,
                              hipStream_t stream) {
    const float* x      = (const float*)d_in[0];
    const float* w_qkv  = (const float*)d_in[1];
    const float* b_qkv  = (const float*)d_in[2];
    const float* w_o    = (const float*)d_in[3];
    const float* b_o    = (const float*)d_in[4];
    const float* lepe_w = (const float*)d_in[5];
    const float* lepe_b = (const float*)d_in[6];
    float* out = (float*)d_out;

    // Workspace layout (~33 MB)
    char* w = (char*)d_ws;
    __bf16* Qp    = (__bf16*)w; w += 6422528;    // [49*8*256*32] bf16
    __bf16* Kp    = (__bf16*)w; w += 6422528;
    __bf16* vbf   = (__bf16*)w; w += 6422528;    // [12544*256] bf16, image layout
    __bf16* Vt    = (__bf16*)w; w += 6422528;    // [49*8*32*256] bf16
    __bf16* prebf = (__bf16*)w; w += 6422528;
    __bf16* wtq   = (__bf16*)w; w += 393216;     // [768*256] bf16
    __bf16* wto   = (__bf16*)w; w += 131072;     // [256*256] bf16
    float* q_win   = (float*)w; w += 12544 * 4;  // q_win,k_win contiguous
    float* k_win   = (float*)w; w += 12544 * 4;
    int*   top_idx = (int*)w;

    pack1<<<768 + 256 + 98, 64, 0, stream>>>(w_qkv, w_o, wtq, wto, q_win);
    gemm_bf16<1><<<dim3(196, 6), 256, 0, stream>>>(nullptr, x, wtq, b_qkv,
                                                   nullptr, 0, Qp, Kp, vbf, Vt,
                                                   q_win, k_win);
    routing_topk<<<49, 64, 0, stream>>>(q_win, k_win, top_idx);
    attn_mfma<<<392 * 4, 256, 0, stream>>>(Qp, Kp, Vt, top_idx,
                                           vbf, lepe_w, lepe_b, prebf);
    gemm_bf16<0><<<dim3(196, 2), 256, 0, stream>>>(prebf, nullptr, wto, b_o,
                                                   out, 256, nullptr, nullptr, nullptr, nullptr,
                                                   nullptr, nullptr);
}

// Round 9
// 156.243 us; speedup vs baseline: 1.0585x; 1.0585x over previous
//
#include <hip/hip_runtime.h>
#include <math.h>

// Problem constants
// DIM=256, QK=256, HEADS=8, NWIN=7, TOPK=4, H=W=112, hw=ww=16, p2=49, w2=256, hd=32
//
// Data flow (all MFMA operands packed bf16, K-contiguous):
//   pack1:    w_qkv -> wtq (T bf16), w_o -> wto, zero q_win/k_win
//   gemm<1>:  x (fp32) staged to LDS as bf16 tile; Wt frags DEPTH-2 register
//             pipeline (+16 VGPR, stays under the 128-VGPR occupancy step --
//             round-8 lesson: full hoist crossed it and lost 8 us); K-loop =
//             ds_read + MFMA. -> Qp (log2e/16 baked), Kp, vbf; V-blocks
//             LDS-transpose to Vt; Q/K blocks window sums via shfl+atomicAdd.
//   routing_topk: window routing indices
//   attn:     flash attention v14: 16-stage QKSM(u+1)/PV(u) pipeline, per-nt
//             P ping-pong; row-sum as per-lane partials, one deferred
//             quad-reduce after the K-loop. LDS 36864 B.
//   gemm<0>:  prebf @ wto -> out fp32 (same depth-2 structure)

typedef __bf16 bf16x8 __attribute__((ext_vector_type(8)));
typedef __bf16 bf16x4 __attribute__((ext_vector_type(4)));
typedef float f32x4 __attribute__((ext_vector_type(4)));

// ---------------------------------------------------------------------------
// pack1: grid 768+256+98 blocks x 64 threads
// ---------------------------------------------------------------------------
__global__ __launch_bounds__(64)
void pack1(const float* __restrict__ w_qkv, const float* __restrict__ w_o,
           __bf16* __restrict__ wtq, __bf16* __restrict__ wto,
           float* __restrict__ qkwin) {
    const int b = blockIdx.x;
    const int t = threadIdx.x;
    if (b < 768) {
        int n = b;
        int k = t * 4;
        bf16x4 o;
        o[0] = (__bf16)w_qkv[(k + 0) * 768 + n];
        o[1] = (__bf16)w_qkv[(k + 1) * 768 + n];
        o[2] = (__bf16)w_qkv[(k + 2) * 768 + n];
        o[3] = (__bf16)w_qkv[(k + 3) * 768 + n];
        *(bf16x4*)(wtq + (size_t)n * 256 + k) = o;
    } else if (b < 1024) {
        int n = b - 768;
        int k = t * 4;
        bf16x4 o;
        o[0] = (__bf16)w_o[(k + 0) * 256 + n];
        o[1] = (__bf16)w_o[(k + 1) * 256 + n];
        o[2] = (__bf16)w_o[(k + 2) * 256 + n];
        o[3] = (__bf16)w_o[(k + 3) * 256 + n];
        *(bf16x4*)(wto + (size_t)n * 256 + k) = o;
    } else {
        int idx = (b - 1024) * 64 + t;
        *(float4*)(qkwin + (size_t)idx * 4) = (float4){0.f, 0.f, 0.f, 0.f};
    }
}

// ---------------------------------------------------------------------------
// bf16 MFMA GEMM: D[n][m] = Wt[n][k] . A[m][k]  (K=256), +bias.
// Block 256 thr = 4 waves. Wave: 32 n (2 frags) x 64 m (4 frags), 8 K-steps.
// A-tile (64 x 256) staged once into LDS (bf16); Wt frags in a DEPTH-2
// register pipeline (each load issued ~2 K-steps before use; ~75 VGPR total).
// LDS: As[64][264] (33792 B) unioned with Vs[128][72] (As dead after K-loop;
// barrier before Vs writes). 4 blocks/CU (LDS-capped).
// ---------------------------------------------------------------------------
template<int QKV>
__global__ __launch_bounds__(256)
void gemm_bf16(const __bf16* __restrict__ A,
               const float* __restrict__ Ax,
               const __bf16* __restrict__ Wt,
               const float* __restrict__ bias,
               float* __restrict__ C, int N,
               __bf16* __restrict__ Qp,
               __bf16* __restrict__ Kp,
               __bf16* __restrict__ vbf,
               __bf16* __restrict__ Vt,
               float* __restrict__ q_win,
               float* __restrict__ k_win) {
    const int t = threadIdx.x & 63;
    const int wv = threadIdx.x >> 6;
    const int l16 = t & 15, quad = t >> 4;
    const int m0 = blockIdx.x * 64;
    const int n0 = blockIdx.y * 128 + wv * 32;

    __shared__ __align__(16) char smem[33792];            // As (33792) | Vs (18432)
    __bf16 (*const As)[264] = (__bf16(*)[264])smem;       // staged A-tile, padded
    __bf16 (*const Vs)[72]  = (__bf16(*)[72])smem;        // V-transpose staging

    // ---- stage A-tile (64 rows x 256) into LDS ----
    if (QKV == 1) {
        // fp32 x (image layout) -> bf16 LDS; block spans one window p
        const int p = m0 >> 8, pixbase = m0 & 255;
        const int rowbase0 = (p / 7) * 16 * 112 + (p % 7) * 16;
#pragma unroll
        for (int it = 0; it < 16; it++) {
            const int j = it * 1024 + threadIdx.x * 4;    // flat float idx
            const int r = j >> 8, col = j & 255;
            const int pix = pixbase + r;
            const int ir = rowbase0 + (pix >> 4) * 112 + (pix & 15);
            const float4 f = *(const float4*)(Ax + (size_t)ir * 256 + col);
            bf16x4 o;
            o[0] = (__bf16)f.x; o[1] = (__bf16)f.y;
            o[2] = (__bf16)f.z; o[3] = (__bf16)f.w;
            *(bf16x4*)&As[r][col] = o;
        }
    } else {
#pragma unroll
        for (int it = 0; it < 8; it++) {
            const int j = it * 2048 + threadIdx.x * 8;    // flat bf16 idx
            const int r = j >> 8, col = j & 255;
            *(bf16x8*)&As[r][col] = *(const bf16x8*)(A + (size_t)(m0 + r) * 256 + col);
        }
    }

    // ---- depth-2 Wt pipeline: preload K-steps 0 and 1 before the barrier ----
    bf16x8 Afbuf[2][2];
#pragma unroll
    for (int km = 0; km < 2; km++) {
        Afbuf[0][km] = *(const bf16x8*)(Wt + (size_t)(n0 + km * 16 + l16) * 256 + 0 * 32 + quad * 8);
        Afbuf[1][km] = *(const bf16x8*)(Wt + (size_t)(n0 + km * 16 + l16) * 256 + 1 * 32 + quad * 8);
    }

    __syncthreads();

    f32x4 acc[2][4];
#pragma unroll
    for (int km = 0; km < 2; km++)
#pragma unroll
        for (int nt = 0; nt < 4; nt++) acc[km][nt] = (f32x4){0.f, 0.f, 0.f, 0.f};

    // ---- K-loop: ds_read + MFMA; Wt loads issued 2 steps ahead ----
#pragma unroll
    for (int ks = 0; ks < 8; ks++) {
        bf16x8 Afn[2];
        if (ks + 2 < 8) {
#pragma unroll
            for (int km = 0; km < 2; km++)
                Afn[km] = *(const bf16x8*)(Wt + (size_t)(n0 + km * 16 + l16) * 256 + (ks + 2) * 32 + quad * 8);
        }

        bf16x8 Bf[4];
#pragma unroll
        for (int nt = 0; nt < 4; nt++)
            Bf[nt] = *(const bf16x8*)&As[nt * 16 + l16][ks * 32 + quad * 8];

        const int slot = ks & 1;
#pragma unroll
        for (int km = 0; km < 2; km++)
#pragma unroll
            for (int nt = 0; nt < 4; nt++)
                acc[km][nt] = __builtin_amdgcn_mfma_f32_16x16x32_bf16(
                    Afbuf[slot][km], Bf[nt], acc[km][nt], 0, 0, 0);

        if (ks + 2 < 8) {
#pragma unroll
            for (int km = 0; km < 2; km++) Afbuf[slot][km] = Afn[km];
        }
    }

    // As is dead; V-blocks will reuse the LDS as Vs
    if (QKV == 1 && blockIdx.y >= 4) __syncthreads();

    float ws[2][4];   // window channel sums (QKV=1, Q/K blocks)
#pragma unroll
    for (int km = 0; km < 2; km++)
#pragma unroll
        for (int j = 0; j < 4; j++) ws[km][j] = 0.f;

#pragma unroll
    for (int km = 0; km < 2; km++) {
        const int n = n0 + km * 16 + quad * 4;
        float4 b4 = *(const float4*)(bias + n);
#pragma unroll
        for (int nt = 0; nt < 4; nt++) {
            const int m = m0 + nt * 16 + l16;
            float v0 = acc[km][nt][0] + b4.x;
            float v1 = acc[km][nt][1] + b4.y;
            float v2 = acc[km][nt][2] + b4.z;
            float v3 = acc[km][nt][3] + b4.w;
            if (QKV == 0) {
                float4 o = {v0, v1, v2, v3};
                *(float4*)(C + (size_t)m * N + n) = o;
            } else {
                const int p = m >> 8, pix = m & 255;
                if (n0 < 512) {
                    ws[km][0] += v0; ws[km][1] += v1;
                    ws[km][2] += v2; ws[km][3] += v3;
                }
                if (n0 < 256) {            // Q -> Qp, log2e/16 scale baked in
                    const float s = 1.4426950408889634f / 16.0f;
                    int h = n >> 5, cc = n & 31;
                    bf16x4 o;
                    o[0] = (__bf16)(v0 * s); o[1] = (__bf16)(v1 * s);
                    o[2] = (__bf16)(v2 * s); o[3] = (__bf16)(v3 * s);
                    *(bf16x4*)(Qp + ((size_t)((p * 8 + h) * 256 + pix)) * 32 + cc) = o;
                } else if (n0 < 512) {     // K -> Kp
                    int n2 = n - 256;
                    int h = n2 >> 5, cc = n2 & 31;
                    bf16x4 o;
                    o[0] = (__bf16)v0; o[1] = (__bf16)v1;
                    o[2] = (__bf16)v2; o[3] = (__bf16)v3;
                    *(bf16x4*)(Kp + ((size_t)((p * 8 + h) * 256 + pix)) * 32 + cc) = o;
                } else {                   // V -> vbf bf16 image + LDS stash
                    int n2 = n - 512;
                    int imgrow = ((p / 7) * 16 + (pix >> 4)) * 112 + (p % 7) * 16 + (pix & 15);
                    bf16x4 o;
                    o[0] = (__bf16)v0; o[1] = (__bf16)v1;
                    o[2] = (__bf16)v2; o[3] = (__bf16)v3;
                    *(bf16x4*)(vbf + (size_t)imgrow * 256 + n2) = o;
                    const int cbase = wv * 32 + km * 16 + quad * 4;   // 0..127
                    const int pb = nt * 16 + l16;                      // 0..63
                    Vs[cbase + 0][pb] = o[0];
                    Vs[cbase + 1][pb] = o[1];
                    Vs[cbase + 2][pb] = o[2];
                    Vs[cbase + 3][pb] = o[3];
                }
            }
        }
    }

    if (QKV == 1 && n0 < 512) {
        const int pblk = m0 >> 8;
#pragma unroll
        for (int km = 0; km < 2; km++) {
#pragma unroll
            for (int j = 0; j < 4; j++) {
                float s = ws[km][j];
                s += __shfl_xor(s, 1);
                s += __shfl_xor(s, 2);
                s += __shfl_xor(s, 4);
                s += __shfl_xor(s, 8);
                ws[km][j] = s;
            }
            if (l16 == 0) {
                const int n = n0 + km * 16 + quad * 4;
                float* dst = (n < 256) ? (q_win + pblk * 256 + n)
                                       : (k_win + pblk * 256 + (n - 256));
                atomicAdd(dst + 0, ws[km][0]);
                atomicAdd(dst + 1, ws[km][1]);
                atomicAdd(dst + 2, ws[km][2]);
                atomicAdd(dst + 3, ws[km][3]);
            }
        }
    }

    if (QKV == 1 && blockIdx.y >= 4) {
        __syncthreads();
        const int p_ = m0 >> 8, qt_ = (m0 >> 6) & 3;
        const int vb = blockIdx.y * 128 - 512;   // 0 or 128
#pragma unroll
        for (int rep = 0; rep < 4; rep++) {
            int id = rep * 256 + threadIdx.x;
            int row = id >> 3, c8 = (id & 7) * 8;
            int hh = (vb + row) >> 5, c32 = (vb + row) & 31;
            bf16x8 val = *(const bf16x8*)&Vs[row][c8];
            *(bf16x8*)(Vt + ((size_t)((p_ * 8 + hh) * 32 + c32)) * 256 + qt_ * 64 + c8) = val;
        }
    }
}

// ---------------------------------------------------------------------------
// Routing: grid 49, 64 threads; lane j = dot(q_win[r], k_win[j]); lane 0 top-4.
// (q_win/k_win are unscaled channel SUMS; dropped factors are positive
//  monotone -> same top-4 set, which is all attn uses.)
// ---------------------------------------------------------------------------
__global__ __launch_bounds__(64)
void routing_topk(const float* __restrict__ q_win,
                  const float* __restrict__ k_win,
                  int* __restrict__ top_idx) {
    const int r = blockIdx.x;
    const int j = threadIdx.x;
    __shared__ float vals[64];

    float d = -1e30f;
    if (j < 49) {
        const float4* qp = (const float4*)(q_win + r * 256);
        const float4* kp = (const float4*)(k_win + j * 256);
        float s = 0.f;
#pragma unroll
        for (int c = 0; c < 64; c++) {
            float4 a = qp[c], b = kp[c];
            s += a.x * b.x + a.y * b.y + a.z * b.z + a.w * b.w;
        }
        d = s;
    }
    vals[j] = d;
    __syncthreads();
    if (j == 0) {
        float bv0 = -1e30f, bv1 = -1e30f, bv2 = -1e30f, bv3 = -1e30f;
        int bi0 = 0, bi1 = 0, bi2 = 0, bi3 = 0;
        for (int q = 0; q < 49; q++) {
            float v = vals[q];
            if (v > bv0) {
                bv3 = bv2; bi3 = bi2; bv2 = bv1; bi2 = bi1; bv1 = bv0; bi1 = bi0;
                bv0 = v; bi0 = q;
            } else if (v > bv1) {
                bv3 = bv2; bi3 = bi2; bv2 = bv1; bi2 = bi1; bv1 = v; bi1 = q;
            } else if (v > bv2) {
                bv3 = bv2; bi3 = bi2; bv2 = v; bi2 = q;
            } else if (v > bv3) {
                bv3 = v; bi3 = q;
            }
        }
        top_idx[r * 4 + 0] = bi0;
        top_idx[r * 4 + 1] = bi1;
        top_idx[r * 4 + 2] = bi2;
        top_idx[r * 4 + 3] = bi3;
    }
}

// ---------------------------------------------------------------------------
// MFMA flash attention v14: 16-stage QKSM/PV pipeline + deferred quad-reduce.
// 4 waves/block (256 thr), grid 1568 XCD-swizzled. Wave wv owns routed
// window sels[wv]. Per-nt P ping-pong; loop body QKSM(u+1) -> PV(u).
// Row-sum: per-lane partials in lstate[] (no in-loop shfl); one 8-shfl
// quad-reduce after the K-loop. K prefetched 1 chunk ahead; V loaded after
// its last use. Fixed-base softmax p=exp2(S). LDS 36864 B; no
// launch_bounds cap (round-5 spill lesson).
// ---------------------------------------------------------------------------
#define PLDS_PITCH 68
#define HALO_PITCH 36   // shorts per halo pixel (32 ch + 4 pad; 72 B)

__global__ __launch_bounds__(256)
void attn_mfma(const __bf16* __restrict__ Qp,
               const __bf16* __restrict__ Kp,
               const __bf16* __restrict__ Vt,
               const int* __restrict__ top_idx,
               const __bf16* __restrict__ vbf,
               const float* __restrict__ lw,
               const float* __restrict__ lb,
               __bf16* __restrict__ prebf) {
    const int bb = blockIdx.x;
    const int qt = bb / 392;
    const int ph = bb - qt * 392;
    const int p = ph >> 3;
    const int h = ph & 7;
    const int t = threadIdx.x & 63;
    const int wv = threadIdx.x >> 6;
    const int l16 = t & 15, quad = t >> 4;

    __shared__ union {
        unsigned short Plds[4][2][16 * PLDS_PITCH];   // 17408 B: per-wave P ping-pong
        struct {
            f32x4 O[4][2][4][64];                     // 32768 B: [wv][mt][nt][t]
            float l[4][4][64];                        //  4096 B: [wv][nt][t]
        } red;                                        // 36864 B
        __bf16 Hs[108 * HALO_PITCH];                  //  7776 B (overlaid later)
    } U;                                              // union size 36864 B

    bf16x8 Qf[4];
#pragma unroll
    for (int nt = 0; nt < 4; nt++)
        Qf[nt] = *(const bf16x8*)(Qp + ((size_t)((p * 8 + h) * 256 + qt * 64 + nt * 16 + l16)) * 32 + quad * 8);

    const int sel = top_idx[p * 4 + wv];
    const __bf16* const Kb = Kp + ((size_t)(sel * 8 + h)) * 8192;
    const __bf16* const Vb = Vt + ((size_t)(sel * 8 + h)) * 8192;

    float lstate[4] = {0.f, 0.f, 0.f, 0.f};
    f32x4 O[2][4];
#pragma unroll
    for (int mt = 0; mt < 2; mt++)
#pragma unroll
        for (int nt = 0; nt < 4; nt++) O[mt][nt] = (f32x4){0.f, 0.f, 0.f, 0.f};

    // preload K chunk 0 and V chunk 0
    bf16x8 Kf[4], Kn[4], Vf[2][2];
#pragma unroll
    for (int km = 0; km < 4; km++)
        Kf[km] = *(const bf16x8*)(Kb + (size_t)(km * 16 + l16) * 32 + quad * 8);
#pragma unroll
    for (int ks = 0; ks < 2; ks++)
#pragma unroll
        for (int mt = 0; mt < 2; mt++)
            Vf[ks][mt] = *(const bf16x8*)(Vb + (size_t)(mt * 16 + l16) * 256 + ks * 32 + quad * 8);

    // stage helpers (inlined; all args compile-time under full unroll)
    auto QKSM = [&](int ntv, int par) {
        f32x4 S[4];
        __builtin_amdgcn_s_setprio(1);
#pragma unroll
        for (int km = 0; km < 4; km++)
            S[km] = __builtin_amdgcn_mfma_f32_16x16x32_bf16(
                Kf[km], Qf[ntv], (f32x4){0.f, 0.f, 0.f, 0.f}, 0, 0, 0);
        __builtin_amdgcn_s_setprio(0);
        unsigned short* const Pp = U.Plds[wv][par];
        float rs = 0.f;
#pragma unroll
        for (int km = 0; km < 4; km++) {
            union { unsigned short u_[4]; ushort4 v; } pk;
#pragma unroll
            for (int r = 0; r < 4; r++) {
                float pv = __builtin_amdgcn_exp2f(S[km][r]);
                rs += pv;
                pk.u_[r] = __builtin_bit_cast(unsigned short, (__bf16)pv);
            }
            *(ushort4*)&Pp[l16 * PLDS_PITCH + km * 16 + quad * 4] = pk.v;
        }
        lstate[ntv] += rs;   // per-lane partial; quad-reduce deferred
    };

    auto PV = [&](int ntv, int par) {
        unsigned short* const Pp = U.Plds[wv][par];
#pragma unroll
        for (int ks = 0; ks < 2; ks++) {
            const int idx = l16 * PLDS_PITCH + ks * 32 + quad * 8;
            union { ushort4 u4[2]; bf16x8 v; } pu;
            pu.u4[0] = *(const ushort4*)&Pp[idx];
            pu.u4[1] = *(const ushort4*)&Pp[idx + 4];
            __builtin_amdgcn_s_setprio(1);
#pragma unroll
            for (int mt = 0; mt < 2; mt++)
                O[mt][ntv] = __builtin_amdgcn_mfma_f32_16x16x32_bf16(
                    Vf[ks][mt], pu.v, O[mt][ntv], 0, 0, 0);
            __builtin_amdgcn_s_setprio(0);
        }
    };

    // prologue: stage 0 -> buf 0
    QKSM(0, 0);

#pragma unroll
    for (int u = 0; u < 16; u++) {
        const int kc = u >> 2, nt = u & 3;
        const int par = u & 1;

        // K prefetch for chunk kc+1 (used 4 stages later)
        if (nt == 0 && kc < 3) {
#pragma unroll
            for (int km = 0; km < 4; km++)
                Kn[km] = *(const bf16x8*)(Kb + (size_t)((kc + 1) * 64 + km * 16 + l16) * 32 + quad * 8);
        }

        if (u < 15) {
            const int ntn = (u + 1) & 3;
            if (ntn == 0) {   // entering next chunk for QK
#pragma unroll
                for (int km = 0; km < 4; km++) Kf[km] = Kn[km];
            }
            QKSM(ntn, par ^ 1);
        }

        PV(nt, par);

        if (nt == 3 && kc < 3) {
            // Vf free after this PV; load next chunk's V
#pragma unroll
            for (int ks = 0; ks < 2; ks++)
#pragma unroll
                for (int mt = 0; mt < 2; mt++)
                    Vf[ks][mt] = *(const bf16x8*)(Vb + (size_t)(mt * 16 + l16) * 256 + (kc + 1) * 64 + ks * 32 + quad * 8);
        }
    }

    // ---- deferred quad-reduce of row sums (8 shfls total) ----
#pragma unroll
    for (int nt2 = 0; nt2 < 4; nt2++) {
        float rs = lstate[nt2];
        rs += __shfl_xor(rs, 16);
        rs += __shfl_xor(rs, 32);
        lstate[nt2] = rs;
    }

    // ---- block-wide combine: partials -> LDS (Plds is dead, reuse) ----
    __syncthreads();
#pragma unroll
    for (int mt = 0; mt < 2; mt++)
#pragma unroll
        for (int nt = 0; nt < 4; nt++)
            U.red.O[wv][mt][nt][t] = O[mt][nt];
#pragma unroll
    for (int nt = 0; nt < 4; nt++)
        U.red.l[wv][nt][t] = lstate[nt];
    __syncthreads();

    // ---- pull combined O,l for this wave's q-row group (nt = wv) to regs ----
    const int nt = wv;
    const float ltot = U.red.l[0][nt][t] + U.red.l[1][nt][t]
                     + U.red.l[2][nt][t] + U.red.l[3][nt][t];
    const float inv = 1.f / ltot;
    f32x4 Osum[2];
#pragma unroll
    for (int mt = 0; mt < 2; mt++) {
        f32x4 o = U.red.O[0][mt][nt][t];
#pragma unroll
        for (int v = 1; v < 4; v++) {
            f32x4 ov = U.red.O[v][mt][nt][t];
            o[0] += ov[0]; o[1] += ov[1]; o[2] += ov[2]; o[3] += ov[3];
        }
        Osum[mt] = o;
    }
    __syncthreads();   // red dead -> Hs may overlay

    // ---- stage 6x18 halo rows into Hs (direct global->LDS) ----
    const int pr = p / 7, pc = p % 7;
    if (threadIdx.x < 108) {
        const int i = threadIdx.x;
        int hy = i / 18, hx = i - hy * 18;
        int gy = pr * 16 + qt * 4 - 1 + hy;
        int gx = pc * 16 - 1 + hx;
        union { bf16x4 v4[8]; bf16x8 v8[4]; uint4 q[4]; } u;
        u.q[0] = (uint4){0u, 0u, 0u, 0u};
        u.q[1] = (uint4){0u, 0u, 0u, 0u};
        u.q[2] = (uint4){0u, 0u, 0u, 0u};
        u.q[3] = (uint4){0u, 0u, 0u, 0u};
        if (gy >= 0 && gy < 112 && gx >= 0 && gx < 112) {
            const __bf16* src = vbf + ((size_t)(gy * 112 + gx)) * 256 + h * 32;
            u.v8[0] = *(const bf16x8*)src;
            u.v8[1] = *(const bf16x8*)(src + 8);
            u.v8[2] = *(const bf16x8*)(src + 16);
            u.v8[3] = *(const bf16x8*)(src + 24);
        }
#pragma unroll
        for (int j = 0; j < 8; j++)
            *(bf16x4*)&U.Hs[i * HALO_PITCH + j * 4] = u.v4[j];
    }
    __syncthreads();

    // ---- epilogue: LePE 3x3 dwconv from Hs + normalize + store ----
    const int himg = pr * 16 + qt * 4 + nt, wimg = pc * 16 + l16;
#pragma unroll
    for (int mt = 0; mt < 2; mt++) {
        const int c = h * 32 + mt * 16 + quad * 4;
        const float4 lbv = *(const float4*)(lb + c);
        float a0 = lbv.x, a1 = lbv.y, a2 = lbv.z, a3 = lbv.w;
#pragma unroll
        for (int dh = 0; dh < 3; dh++)
#pragma unroll
            for (int dw = 0; dw < 3; dw++) {
                const float4 w4 = *(const float4*)(lw + (dh * 3 + dw) * 256 + c);
                const bf16x4 v4 = *(const bf16x4*)&U.Hs[((nt + dh) * 18 + l16 + dw) * HALO_PITCH + mt * 16 + quad * 4];
                a0 += (float)v4[0] * w4.x;
                a1 += (float)v4[1] * w4.y;
                a2 += (float)v4[2] * w4.z;
                a3 += (float)v4[3] * w4.w;
            }
        bf16x4 ob;
        ob[0] = (__bf16)(Osum[mt][0] * inv + a0);
        ob[1] = (__bf16)(Osum[mt][1] * inv + a1);
        ob[2] = (__bf16)(Osum[mt][2] * inv + a2);
        ob[3] = (__bf16)(Osum[mt][3] * inv + a3);
        *(bf16x4*)(prebf + ((size_t)(himg * 112 + wimg)) * 256 + c) = ob;
    }
}

// ---------------------------------------------------------------------------
extern "C" void kernel_launch(void* const* d_in, const int* in_sizes, int n_in,
                              void* d_out, int out_size, void* d_ws, size_t ws_size,
                              hipStream_t stream) {
    const float* x      = (const float*)d_in[0];
    const float* w_qkv  = (const float*)d_in[1];
    const float* b_qkv  = (const float*)d_in[2];
    const float* w_o    = (const float*)d_in[3];
    const float* b_o    = (const float*)d_in[4];
    const float* lepe_w = (const float*)d_in[5];
    const float* lepe_b = (const float*)d_in[6];
    float* out = (float*)d_out;

    // Workspace layout (~33 MB)
    char* w = (char*)d_ws;
    __bf16* Qp    = (__bf16*)w; w += 6422528;    // [49*8*256*32] bf16
    __bf16* Kp    = (__bf16*)w; w += 6422528;
    __bf16* vbf   = (__bf16*)w; w += 6422528;    // [12544*256] bf16, image layout
    __bf16* Vt    = (__bf16*)w; w += 6422528;    // [49*8*32*256] bf16
    __bf16* prebf = (__bf16*)w; w += 6422528;
    __bf16* wtq   = (__bf16*)w; w += 393216;     // [768*256] bf16
    __bf16* wto   = (__bf16*)w; w += 131072;     // [256*256] bf16
    float* q_win   = (float*)w; w += 12544 * 4;  // q_win,k_win contiguous
    float* k_win   = (float*)w; w += 12544 * 4;
    int*   top_idx = (int*)w;

    pack1<<<768 + 256 + 98, 64, 0, stream>>>(w_qkv, w_o, wtq, wto, q_win);
    gemm_bf16<1><<<dim3(196, 6), 256, 0, stream>>>(nullptr, x, wtq, b_qkv,
                                                   nullptr, 0, Qp, Kp, vbf, Vt,
                                                   q_win, k_win);
    routing_topk<<<49, 64, 0, stream>>>(q_win, k_win, top_idx);
    attn_mfma<<<392 * 4, 256, 0, stream>>>(Qp, Kp, Vt, top_idx,
                                           vbf, lepe_w, lepe_b, prebf);
    gemm_bf16<0><<<dim3(196, 2), 256, 0, stream>>>(prebf, nullptr, wto, b_o,
                                                   out, 256, nullptr, nullptr, nullptr, nullptr,
                                                   nullptr, nullptr);
}